// Round 5
// baseline (12310.666 us; speedup 1.0000x reference)
//
#include <hip/hip_runtime.h>

#define T_STEPS 2048
#define BATCH 8
#define HID 1024

// ws layout:
//   floats [0, 50331648)      x_proj repacked [b][t][gate][j]: ((b*2048+t)*3+g)*1024 + j
//   byte 201326592 (=192MiB): h double buffer, 2 x 4096 u64, each u64 packs TWO fp32 h
//                             values {hi = h(2q+1) clean, lo = h(2q) with bit30 = tag}.
//                             slot = parity*4096 + b*512 + q; production step s -> parity s&1,
//                             tagbit(s) = ((s>>1)&1)^1. |h|<1 (clamped) => real bit30 == 0.
//                             ws poison 0xAAAAAAAA has bit30=0 != tagbit(0)=1, so poison
//                             never validates. 64 KiB total.
//
// R5-resident-wf-slack: R3/R4's identical twice-failures are read as a co-residency
// deadlock, not infra: __launch_bounds__(512,2) => exactly 1 block/CU, 256 blocks on
// 256 CUs with ZERO slack; any busy CU strands a block whose tags the rest spin on.
// This round keeps the resident-W_hh theory (R2's regression proved W_hh was being
// re-streamed from L2/L3 every step: VGPR_Count 132/220 << fragment size) but with
// 4-wave blocks and 2x slack: 2 groups x 128 blocks, block owns (4 batches x 8 j),
// wave owns (4 b x 2 j) -> per-lane fragment 3x2x16 = 96 floats, volatile-loaded +
// asm-pinned. __launch_bounds__(256,2) caps VGPR at 256 -> 2 blocks/CU capacity ->
// 512 residency slots for 256 blocks.
#define XPROJ_F 50331648ull
#define HBUF64_BYTE_OFF 201326592ull

__device__ __forceinline__ float sigmoidf_(float x) {
    return 1.0f / (1.0f + __expf(-x));
}

// Relaxed AGENT-scope atomics lower to global_load/store ... sc1 — they read/
// write the Infinity Cache (the inter-XCD coherence point) with NO L2
// writeback/invalidate. An aligned 8B store is single-copy atomic, so the
// packed {tag|h_even, h_odd} packet is self-validating: no flags, no fences.
__device__ __forceinline__ unsigned long long ld_u64_agent(const unsigned long long* p) {
    return __hip_atomic_load(p, __ATOMIC_RELAXED, __HIP_MEMORY_SCOPE_AGENT);
}
__device__ __forceinline__ void st_u64_agent(unsigned long long* p, unsigned long long v) {
    __hip_atomic_store(p, v, __ATOMIC_RELAXED, __HIP_MEMORY_SCOPE_AGENT);
}

// ---------------- Phase 1: x_proj = x @ W_ih^T + b_ih ----------------
// 128x128 tile, BK=16, 256 threads, 8x8 micro-tile. Epilogue writes the
// [b][t][g][j] layout the scan wants (j-contiguous -> two float4 stores/row).
__global__ __launch_bounds__(256) void gemm_xproj(
        const float* __restrict__ x, const float* __restrict__ Wih,
        const float* __restrict__ bih, float* __restrict__ xproj) {
    __shared__ float a_lds[16][128];  // [k][m]
    __shared__ float b_lds[16][128];  // [k][n]
    const int tid = threadIdx.x;
    const int m0 = blockIdx.x * 128;
    const int n0 = blockIdx.y * 128;
    const int tx = tid & 15, ty = tid >> 4;

    float acc[8][8];
#pragma unroll
    for (int i = 0; i < 8; i++)
#pragma unroll
        for (int jj = 0; jj < 8; jj++) acc[i][jj] = 0.f;

    for (int k0 = 0; k0 < 1024; k0 += 16) {
#pragma unroll
        for (int l = 0; l < 2; l++) {
            const int c = tid + l * 256;
            const int row = c >> 2;
            const int f4 = c & 3;
            float4 av = *reinterpret_cast<const float4*>(
                x + (size_t)(m0 + row) * 1024 + k0 + f4 * 4);
            float4 bv = *reinterpret_cast<const float4*>(
                Wih + (size_t)(n0 + row) * 1024 + k0 + f4 * 4);
            a_lds[f4 * 4 + 0][row] = av.x; a_lds[f4 * 4 + 1][row] = av.y;
            a_lds[f4 * 4 + 2][row] = av.z; a_lds[f4 * 4 + 3][row] = av.w;
            b_lds[f4 * 4 + 0][row] = bv.x; b_lds[f4 * 4 + 1][row] = bv.y;
            b_lds[f4 * 4 + 2][row] = bv.z; b_lds[f4 * 4 + 3][row] = bv.w;
        }
        __syncthreads();
#pragma unroll
        for (int kk = 0; kk < 16; kk++) {
            float a[8], b[8];
            *reinterpret_cast<float4*>(&a[0]) =
                *reinterpret_cast<float4*>(&a_lds[kk][ty * 8]);
            *reinterpret_cast<float4*>(&a[4]) =
                *reinterpret_cast<float4*>(&a_lds[kk][ty * 8 + 4]);
            *reinterpret_cast<float4*>(&b[0]) =
                *reinterpret_cast<float4*>(&b_lds[kk][tx * 8]);
            *reinterpret_cast<float4*>(&b[4]) =
                *reinterpret_cast<float4*>(&b_lds[kk][tx * 8 + 4]);
#pragma unroll
            for (int i = 0; i < 8; i++)
#pragma unroll
                for (int jj = 0; jj < 8; jj++)
                    acc[i][jj] = fmaf(a[i], b[jj], acc[i][jj]);
        }
        __syncthreads();
    }

    float bias[8];
    *reinterpret_cast<float4*>(&bias[0]) =
        *reinterpret_cast<const float4*>(bih + n0 + tx * 8);
    *reinterpret_cast<float4*>(&bias[4]) =
        *reinterpret_cast<const float4*>(bih + n0 + tx * 8 + 4);
    // m = b*T + t; 128-row m-tiles never straddle a batch (T=2048 % 128 == 0).
    // n-tile (128 wide) never straddles a gate (1024 % 128 == 0).
    const int n_base = n0 + tx * 8;
    const int g = n_base >> 10;
    const int j0 = n_base & 1023;
#pragma unroll
    for (int i = 0; i < 8; i++) {
        const int m = m0 + ty * 8 + i;
        const int b = m >> 11;        // m / 2048
        const int t = m & 2047;
        float* dst = xproj + (((size_t)b * 2048 + t) * 3 + g) * 1024 + j0;
        float4 r0 = {acc[i][0] + bias[0], acc[i][1] + bias[1],
                     acc[i][2] + bias[2], acc[i][3] + bias[3]};
        float4 r1 = {acc[i][4] + bias[4], acc[i][5] + bias[5],
                     acc[i][6] + bias[6], acc[i][7] + bias[7]};
        *reinterpret_cast<float4*>(dst) = r0;
        *reinterpret_cast<float4*>(dst + 4) = r1;
    }
}

// ---------------- Phase 2: sequential GRU scan ----------------
// 256 blocks x 256 threads (4 waves), >=2 blocks/CU schedulable (2x slack).
// group = bid&1 (2 groups x 128 blocks) owns batches 4g..4g+3 — independent
// sync domains. Block gb = bid>>1 owns j in [gb*8, gb*8+8); wave w owns the
// j pair jb_w = gb*8 + w*2 for ALL 4 batches. Per lane: 3 gates x 2 j x
// 16 k x 4 batches = 384 FMA; W_hh fragment = 96 VGPR, volatile + asm-pinned.
// Lane assignment c = lane&7: bb = lane&3, jj = (lane>>2)&1.
// Per step: prefetch gx -> 8 packed-tagged u64 loads -> retry stale ->
// unpack to LDS (dbuf) -> sync -> matvec -> 30-shuffle value-fold reduce ->
// gates on all lanes -> 4 packed u64 stores/wave + out stores (lanes 0..7).
__global__ __launch_bounds__(256, 2) void gru_scan(
        const float* __restrict__ Whh, const float* __restrict__ bhh,
        const float* __restrict__ xproj, float* __restrict__ out,
        unsigned long long* __restrict__ hbuf64) {
    __shared__ float hshare[2][4][HID];   // 32 KB, [parity][b_local][j]
    const int tid = threadIdx.x;
    const int bid = blockIdx.x;
    const int wave = tid >> 6;            // 0..3
    const int lane = tid & 63;
    const int group = bid & 1;            // 2 groups
    const int gb = bid >> 1;              // block within group, 0..127
    const int b0 = group * 4;             // first of this group's 4 batches
    const int jb_w = gb * 8 + wave * 2;   // wave's j pair (even base)

    // lane's output assignment: c = (jj<<2)|bb repeats every 8 lanes
    const int bb_l = lane & 3;
    const int jj_l = (lane >> 2) & 1;
    const int j_l = jb_w + jj_l;
    const int b_l = b0 + bb_l;

    // loop-invariant W_hh fragment: rows g*1024 + (jb_w+jj), k = lane + 64*i.
    // VOLATILE loads cannot be rematerialized/sunk into the t-loop; the asm
    // pin forces one-time materialization into VGPRs (96 regs, resident for
    // the whole scan — one-time 96KB/block instead of per-step re-stream).
    const volatile float* Wv = Whh;
    float wf[3][2][16];
#pragma unroll
    for (int g = 0; g < 3; g++)
#pragma unroll
        for (int jj = 0; jj < 2; jj++)
#pragma unroll
            for (int i = 0; i < 16; i++) {
                wf[g][jj][i] =
                    Wv[(size_t)(g * 1024 + jb_w + jj) * 1024 + lane + 64 * i];
                asm volatile("" : "+v"(wf[g][jj][i]));
            }

    const float bh0 = bhh[j_l];
    const float bh1 = bhh[1024 + j_l];
    const float bh2 = bhh[2048 + j_l];
    const float CL = 0x1.fffffep-1f;   // largest float < 1: keeps bit30 == 0

    // ---- t = 0: h_prev = 0 -> g_h = b_hh ----
    {
        const size_t xb = ((size_t)b_l * 2048 + 0) * 3072 + j_l;
        const float gxr = xproj[xb];
        const float gxz = xproj[xb + 1024];
        const float gxn = xproj[xb + 2048];
        const float r = sigmoidf_(gxr + bh0);
        const float z = sigmoidf_(gxz + bh1);
        const float n = tanhf(gxn + r * bh2);
        float hnew = (1.f - z) * n;
        hnew = fminf(fmaxf(hnew, -CL), CL);
        const float hodd = __shfl_xor(hnew, 4);   // jj=0 lane gets jj=1 value
        const unsigned lo = __float_as_uint(hnew) | (1u << 30);  // tagbit(0)=1
        const unsigned hi = __float_as_uint(hodd);
        if (lane < 4)   // lane = bb: one packed u64 per (wave, batch)
            st_u64_agent(hbuf64 + (size_t)(b0 + lane) * 512 + (jb_w >> 1),
                         ((unsigned long long)hi << 32) | lo);
        if (lane < 8)
            out[((size_t)b_l * 2048 + 0) * 1024 + j_l] = hnew;
    }

    for (int t = 1; t < T_STEPS; t++) {
        // prefetch gx (cached broadcast loads, overlap the staging latency)
        const size_t xb = ((size_t)b_l * 2048 + t) * 3072 + j_l;
        const float gxr = xproj[xb];
        const float gxz = xproj[xb + 1024];
        const float gxn = xproj[xb + 2048];

        // ---- stage h(t-1) for 4 batches: 8 packed tagged u64 loads ----
        const int par = (t - 1) & 1;
        const unsigned long long* src =
            hbuf64 + (size_t)par * 4096 + (size_t)b0 * 512;
        const unsigned expect = (((unsigned)(t - 1) >> 1) & 1u) ^ 1u;
        unsigned long long v[8];
#pragma unroll
        for (int i = 0; i < 8; i++)
            v[i] = ld_u64_agent(src + tid + 256 * i);
        for (;;) {
            unsigned bad = 0;
#pragma unroll
            for (int i = 0; i < 8; i++)
                bad |= (((unsigned)(v[i] >> 30)) & 1u) ^ expect;
            if (bad == 0) break;
            __builtin_amdgcn_s_sleep(1);
#pragma unroll
            for (int i = 0; i < 8; i++)
                if ((((unsigned)(v[i] >> 30)) & 1u) != expect)
                    v[i] = ld_u64_agent(src + tid + 256 * i);
        }
        {
            // packed slot q = tid + 256*i maps to flat float index 2q within
            // hshare[par] (q = bb*512 + s -> flat = bb*1024 + 2s = 2q).
            float2* hflat2 = reinterpret_cast<float2*>(&hshare[par][0][0]);
#pragma unroll
            for (int i = 0; i < 8; i++) {
                float2 p;
                p.x = __uint_as_float((unsigned)v[i] & 0xBFFFFFFFu);
                p.y = __uint_as_float((unsigned)(v[i] >> 32));
                hflat2[tid + 256 * i] = p;
            }
        }
        __syncthreads();   // whole block validated + staged h(t-1)
        // (no trailing barrier: next step stages into the other parity half)

        const float hprev = hshare[par][bb_l][j_l];

        float acc[3][8];   // [g][c], c = (jj<<2)|bb
#pragma unroll
        for (int g = 0; g < 3; g++)
#pragma unroll
            for (int q = 0; q < 8; q++) acc[g][q] = 0.f;
#pragma unroll
        for (int bb = 0; bb < 4; bb++) {
            float hv[16];
#pragma unroll
            for (int i = 0; i < 16; i++)
                hv[i] = hshare[par][bb][lane + 64 * i];
#pragma unroll
            for (int g = 0; g < 3; g++)
#pragma unroll
                for (int jj = 0; jj < 2; jj++)
#pragma unroll
                    for (int i = 0; i < 16; i++)
                        acc[g][(jj << 2) | bb] =
                            fmaf(wf[g][jj][i], hv[i], acc[g][(jj << 2) | bb]);
        }

        // ---- value-folding reduce over the 64-way K split ----
        // Fold c bit0/1/2 against lane bit0/1/2, then 3 butterfly stages;
        // lane l ends with the full sums for c = l&7. 30 shuffles total.
        float a4[3][4];
#pragma unroll
        for (int g = 0; g < 3; g++)
#pragma unroll
            for (int k = 0; k < 4; k++) {
                const float e = acc[g][2 * k], o = acc[g][2 * k + 1];
                const float give = (lane & 1) ? e : o;
                const float keep = (lane & 1) ? o : e;
                a4[g][k] = keep + __shfl_xor(give, 1);
            }
        float a2[3][2];
#pragma unroll
        for (int g = 0; g < 3; g++)
#pragma unroll
            for (int k = 0; k < 2; k++) {
                const float e = a4[g][2 * k], o = a4[g][2 * k + 1];
                const float give = (lane & 2) ? e : o;
                const float keep = (lane & 2) ? o : e;
                a2[g][k] = keep + __shfl_xor(give, 2);
            }
        float a1[3];
#pragma unroll
        for (int g = 0; g < 3; g++) {
            const float e = a2[g][0], o = a2[g][1];
            const float give = (lane & 4) ? e : o;
            const float keep = (lane & 4) ? o : e;
            a1[g] = keep + __shfl_xor(give, 4);
        }
#pragma unroll
        for (int m = 8; m <= 32; m <<= 1)
#pragma unroll
            for (int g = 0; g < 3; g++) a1[g] += __shfl_xor(a1[g], m);

        // ---- gates on all lanes (a1 valid for c = lane&7 on every lane) ----
        const float r = sigmoidf_(gxr + a1[0] + bh0);
        const float z = sigmoidf_(gxz + a1[1] + bh1);
        const float n = tanhf(gxn + r * (a1[2] + bh2));
        float hnew = (1.f - z) * n + z * hprev;
        hnew = fminf(fmaxf(hnew, -CL), CL);
        const float hodd = __shfl_xor(hnew, 4);
        const unsigned tagst = (((unsigned)t >> 1) & 1u) ^ 1u;
        const unsigned lo = __float_as_uint(hnew) | (tagst << 30);
        const unsigned hi = __float_as_uint(hodd);
        if (lane < 4)
            st_u64_agent(hbuf64 + (size_t)(t & 1) * 4096 +
                             (size_t)(b0 + lane) * 512 + (jb_w >> 1),
                         ((unsigned long long)hi << 32) | lo);
        if (lane < 8)
            out[((size_t)b_l * 2048 + t) * 1024 + j_l] = hnew;
    }
}

extern "C" void kernel_launch(void* const* d_in, const int* in_sizes, int n_in,
                              void* d_out, int out_size, void* d_ws,
                              size_t ws_size, hipStream_t stream) {
    const float* x    = (const float*)d_in[0];
    const float* Wih  = (const float*)d_in[1];
    const float* bih  = (const float*)d_in[2];
    const float* Whh  = (const float*)d_in[3];
    const float* bhh  = (const float*)d_in[4];
    float* outp = (float*)d_out;

    float* xproj = (float*)d_ws;
    unsigned long long* hbuf64 =
        (unsigned long long*)((char*)d_ws + HBUF64_BYTE_OFF);

    dim3 g1(128, 24);   // M/128, N/128
    gemm_xproj<<<g1, 256, 0, stream>>>(x, Wih, bih, xproj);
    gru_scan<<<256, 256, 0, stream>>>(Whh, bhh, xproj, outp, hbuf64);
}

// Round 6
// 12301.214 us; speedup vs baseline: 1.0008x; 1.0008x over previous
//
#include <hip/hip_runtime.h>

#define T_STEPS 2048
#define BATCH 8
#define HID 1024

// ws layout:
//   floats [0, 50331648)      x_proj repacked [b][t][gate][j]: ((b*2048+t)*3+g)*1024 + j
//   byte 201326592 (=192MiB): h double buffer, 2 x 4096 u64, each u64 packs TWO fp32 h
//                             values {hi = h(2q+1) clean, lo = h(2q) with bit30 = tag}.
//                             slot = parity*4096 + b*512 + q; production step s -> parity s&1,
//                             tagbit(s) = ((s>>1)&1)^1. |h|<1 (clamped) => real bit30 == 0.
//                             ws poison 0xAAAAAAAA has bit30=0 != tagbit(0)=1, so poison
//                             never validates. 64 KiB total.
//
// R6-pin-occupancy: R5's VGPR_Count=84 (~512/6) proved the failure mode was never the
// register BUDGET — LLVM's occupancy heuristic targeted 6 waves/EU (impossible at this
// 1-block/CU launch) and spilled the volatile-loaded W_hh fragment to scratch, turning
// the matvec into a serial scratch-reload chain (FETCH 833MB, VALUBusy 19.6%, 11.2ms).
// amdgpu_waves_per_eu(2,2) pins the target to exactly 2 waves/EU -> budget 256 VGPRs
// with no incentive to spill below it; the 96-float volatile+asm-pinned fragment now
// genuinely stays register-resident. Geometry unchanged from R5 (passed, 2x residency
// slack): 2 groups x 128 blocks, block owns (4 batches x 8 j), wave owns (4 b x 2 j).
#define XPROJ_F 50331648ull
#define HBUF64_BYTE_OFF 201326592ull

__device__ __forceinline__ float sigmoidf_(float x) {
    return 1.0f / (1.0f + __expf(-x));
}

// Relaxed AGENT-scope atomics lower to global_load/store ... sc1 — they read/
// write the Infinity Cache (the inter-XCD coherence point) with NO L2
// writeback/invalidate. An aligned 8B store is single-copy atomic, so the
// packed {tag|h_even, h_odd} packet is self-validating: no flags, no fences.
__device__ __forceinline__ unsigned long long ld_u64_agent(const unsigned long long* p) {
    return __hip_atomic_load(p, __ATOMIC_RELAXED, __HIP_MEMORY_SCOPE_AGENT);
}
__device__ __forceinline__ void st_u64_agent(unsigned long long* p, unsigned long long v) {
    __hip_atomic_store(p, v, __ATOMIC_RELAXED, __HIP_MEMORY_SCOPE_AGENT);
}

// ---------------- Phase 1: x_proj = x @ W_ih^T + b_ih ----------------
// 128x128 tile, BK=16, 256 threads, 8x8 micro-tile. Epilogue writes the
// [b][t][g][j] layout the scan wants (j-contiguous -> two float4 stores/row).
__global__ __launch_bounds__(256) void gemm_xproj(
        const float* __restrict__ x, const float* __restrict__ Wih,
        const float* __restrict__ bih, float* __restrict__ xproj) {
    __shared__ float a_lds[16][128];  // [k][m]
    __shared__ float b_lds[16][128];  // [k][n]
    const int tid = threadIdx.x;
    const int m0 = blockIdx.x * 128;
    const int n0 = blockIdx.y * 128;
    const int tx = tid & 15, ty = tid >> 4;

    float acc[8][8];
#pragma unroll
    for (int i = 0; i < 8; i++)
#pragma unroll
        for (int jj = 0; jj < 8; jj++) acc[i][jj] = 0.f;

    for (int k0 = 0; k0 < 1024; k0 += 16) {
#pragma unroll
        for (int l = 0; l < 2; l++) {
            const int c = tid + l * 256;
            const int row = c >> 2;
            const int f4 = c & 3;
            float4 av = *reinterpret_cast<const float4*>(
                x + (size_t)(m0 + row) * 1024 + k0 + f4 * 4);
            float4 bv = *reinterpret_cast<const float4*>(
                Wih + (size_t)(n0 + row) * 1024 + k0 + f4 * 4);
            a_lds[f4 * 4 + 0][row] = av.x; a_lds[f4 * 4 + 1][row] = av.y;
            a_lds[f4 * 4 + 2][row] = av.z; a_lds[f4 * 4 + 3][row] = av.w;
            b_lds[f4 * 4 + 0][row] = bv.x; b_lds[f4 * 4 + 1][row] = bv.y;
            b_lds[f4 * 4 + 2][row] = bv.z; b_lds[f4 * 4 + 3][row] = bv.w;
        }
        __syncthreads();
#pragma unroll
        for (int kk = 0; kk < 16; kk++) {
            float a[8], b[8];
            *reinterpret_cast<float4*>(&a[0]) =
                *reinterpret_cast<float4*>(&a_lds[kk][ty * 8]);
            *reinterpret_cast<float4*>(&a[4]) =
                *reinterpret_cast<float4*>(&a_lds[kk][ty * 8 + 4]);
            *reinterpret_cast<float4*>(&b[0]) =
                *reinterpret_cast<float4*>(&b_lds[kk][tx * 8]);
            *reinterpret_cast<float4*>(&b[4]) =
                *reinterpret_cast<float4*>(&b_lds[kk][tx * 8 + 4]);
#pragma unroll
            for (int i = 0; i < 8; i++)
#pragma unroll
                for (int jj = 0; jj < 8; jj++)
                    acc[i][jj] = fmaf(a[i], b[jj], acc[i][jj]);
        }
        __syncthreads();
    }

    float bias[8];
    *reinterpret_cast<float4*>(&bias[0]) =
        *reinterpret_cast<const float4*>(bih + n0 + tx * 8);
    *reinterpret_cast<float4*>(&bias[4]) =
        *reinterpret_cast<const float4*>(bih + n0 + tx * 8 + 4);
    // m = b*T + t; 128-row m-tiles never straddle a batch (T=2048 % 128 == 0).
    // n-tile (128 wide) never straddles a gate (1024 % 128 == 0).
    const int n_base = n0 + tx * 8;
    const int g = n_base >> 10;
    const int j0 = n_base & 1023;
#pragma unroll
    for (int i = 0; i < 8; i++) {
        const int m = m0 + ty * 8 + i;
        const int b = m >> 11;        // m / 2048
        const int t = m & 2047;
        float* dst = xproj + (((size_t)b * 2048 + t) * 3 + g) * 1024 + j0;
        float4 r0 = {acc[i][0] + bias[0], acc[i][1] + bias[1],
                     acc[i][2] + bias[2], acc[i][3] + bias[3]};
        float4 r1 = {acc[i][4] + bias[4], acc[i][5] + bias[5],
                     acc[i][6] + bias[6], acc[i][7] + bias[7]};
        *reinterpret_cast<float4*>(dst) = r0;
        *reinterpret_cast<float4*>(dst + 4) = r1;
    }
}

// ---------------- Phase 2: sequential GRU scan ----------------
// 256 blocks x 256 threads (4 waves), capacity 2 blocks/CU (2x residency slack).
// amdgpu_waves_per_eu(2,2) pins the register allocator's occupancy target to
// exactly 2 waves/EU -> VGPR budget 256, no spill-for-occupancy (R5's VGPR=84
// scratch-spill pathology). group = bid&1 (2 groups x 128 blocks) owns batches
// 4g..4g+3 — independent sync domains. Block gb = bid>>1 owns j in [gb*8,
// gb*8+8); wave w owns the j pair jb_w = gb*8 + w*2 for ALL 4 batches.
// Per lane: 3 gates x 2 j x 16 k x 4 batches = 384 FMA; W_hh fragment =
// 96 VGPR, volatile + asm-pinned, genuinely resident this time.
// Lane assignment c = lane&7: bb = lane&3, jj = (lane>>2)&1.
// Per step: prefetch gx -> 8 packed-tagged u64 loads -> retry stale ->
// unpack to LDS (dbuf) -> sync -> matvec -> 30-shuffle value-fold reduce ->
// gates on all lanes -> 4 packed u64 stores/wave + out stores (lanes 0..7).
__global__ __launch_bounds__(256, 2)
__attribute__((amdgpu_waves_per_eu(2, 2))) void gru_scan(
        const float* __restrict__ Whh, const float* __restrict__ bhh,
        const float* __restrict__ xproj, float* __restrict__ out,
        unsigned long long* __restrict__ hbuf64) {
    __shared__ float hshare[2][4][HID];   // 32 KB, [parity][b_local][j]
    const int tid = threadIdx.x;
    const int bid = blockIdx.x;
    const int wave = tid >> 6;            // 0..3
    const int lane = tid & 63;
    const int group = bid & 1;            // 2 groups
    const int gb = bid >> 1;              // block within group, 0..127
    const int b0 = group * 4;             // first of this group's 4 batches
    const int jb_w = gb * 8 + wave * 2;   // wave's j pair (even base)

    // lane's output assignment: c = (jj<<2)|bb repeats every 8 lanes
    const int bb_l = lane & 3;
    const int jj_l = (lane >> 2) & 1;
    const int j_l = jb_w + jj_l;
    const int b_l = b0 + bb_l;

    // loop-invariant W_hh fragment: rows g*1024 + (jb_w+jj), k = lane + 64*i.
    // VOLATILE loads cannot be rematerialized/sunk into the t-loop; the asm
    // pin forces materialization; waves_per_eu(2,2) gives the allocator a
    // 256-VGPR budget with no occupancy incentive to spill. 96 regs resident.
    const volatile float* Wv = Whh;
    float wf[3][2][16];
#pragma unroll
    for (int g = 0; g < 3; g++)
#pragma unroll
        for (int jj = 0; jj < 2; jj++)
#pragma unroll
            for (int i = 0; i < 16; i++) {
                wf[g][jj][i] =
                    Wv[(size_t)(g * 1024 + jb_w + jj) * 1024 + lane + 64 * i];
                asm volatile("" : "+v"(wf[g][jj][i]));
            }

    const float bh0 = bhh[j_l];
    const float bh1 = bhh[1024 + j_l];
    const float bh2 = bhh[2048 + j_l];
    const float CL = 0x1.fffffep-1f;   // largest float < 1: keeps bit30 == 0

    // ---- t = 0: h_prev = 0 -> g_h = b_hh ----
    {
        const size_t xb = ((size_t)b_l * 2048 + 0) * 3072 + j_l;
        const float gxr = xproj[xb];
        const float gxz = xproj[xb + 1024];
        const float gxn = xproj[xb + 2048];
        const float r = sigmoidf_(gxr + bh0);
        const float z = sigmoidf_(gxz + bh1);
        const float n = tanhf(gxn + r * bh2);
        float hnew = (1.f - z) * n;
        hnew = fminf(fmaxf(hnew, -CL), CL);
        const float hodd = __shfl_xor(hnew, 4);   // jj=0 lane gets jj=1 value
        const unsigned lo = __float_as_uint(hnew) | (1u << 30);  // tagbit(0)=1
        const unsigned hi = __float_as_uint(hodd);
        if (lane < 4)   // lane = bb: one packed u64 per (wave, batch)
            st_u64_agent(hbuf64 + (size_t)(b0 + lane) * 512 + (jb_w >> 1),
                         ((unsigned long long)hi << 32) | lo);
        if (lane < 8)
            out[((size_t)b_l * 2048 + 0) * 1024 + j_l] = hnew;
    }

    for (int t = 1; t < T_STEPS; t++) {
        // prefetch gx (cached broadcast loads, overlap the staging latency)
        const size_t xb = ((size_t)b_l * 2048 + t) * 3072 + j_l;
        const float gxr = xproj[xb];
        const float gxz = xproj[xb + 1024];
        const float gxn = xproj[xb + 2048];

        // ---- stage h(t-1) for 4 batches: 8 packed tagged u64 loads ----
        const int par = (t - 1) & 1;
        const unsigned long long* src =
            hbuf64 + (size_t)par * 4096 + (size_t)b0 * 512;
        const unsigned expect = (((unsigned)(t - 1) >> 1) & 1u) ^ 1u;
        unsigned long long v[8];
#pragma unroll
        for (int i = 0; i < 8; i++)
            v[i] = ld_u64_agent(src + tid + 256 * i);
        for (;;) {
            unsigned bad = 0;
#pragma unroll
            for (int i = 0; i < 8; i++)
                bad |= (((unsigned)(v[i] >> 30)) & 1u) ^ expect;
            if (bad == 0) break;
            __builtin_amdgcn_s_sleep(1);
#pragma unroll
            for (int i = 0; i < 8; i++)
                if ((((unsigned)(v[i] >> 30)) & 1u) != expect)
                    v[i] = ld_u64_agent(src + tid + 256 * i);
        }
        {
            // packed slot q = tid + 256*i maps to flat float index 2q within
            // hshare[par] (q = bb*512 + s -> flat = bb*1024 + 2s = 2q).
            float2* hflat2 = reinterpret_cast<float2*>(&hshare[par][0][0]);
#pragma unroll
            for (int i = 0; i < 8; i++) {
                float2 p;
                p.x = __uint_as_float((unsigned)v[i] & 0xBFFFFFFFu);
                p.y = __uint_as_float((unsigned)(v[i] >> 32));
                hflat2[tid + 256 * i] = p;
            }
        }
        __syncthreads();   // whole block validated + staged h(t-1)
        // (no trailing barrier: next step stages into the other parity half)

        const float hprev = hshare[par][bb_l][j_l];

        float acc[3][8];   // [g][c], c = (jj<<2)|bb
#pragma unroll
        for (int g = 0; g < 3; g++)
#pragma unroll
            for (int q = 0; q < 8; q++) acc[g][q] = 0.f;
#pragma unroll
        for (int bb = 0; bb < 4; bb++) {
            float hv[16];
#pragma unroll
            for (int i = 0; i < 16; i++)
                hv[i] = hshare[par][bb][lane + 64 * i];
#pragma unroll
            for (int g = 0; g < 3; g++)
#pragma unroll
                for (int jj = 0; jj < 2; jj++)
#pragma unroll
                    for (int i = 0; i < 16; i++)
                        acc[g][(jj << 2) | bb] =
                            fmaf(wf[g][jj][i], hv[i], acc[g][(jj << 2) | bb]);
        }

        // ---- value-folding reduce over the 64-way K split ----
        // Fold c bit0/1/2 against lane bit0/1/2, then 3 butterfly stages;
        // lane l ends with the full sums for c = l&7. 30 shuffles total.
        float a4[3][4];
#pragma unroll
        for (int g = 0; g < 3; g++)
#pragma unroll
            for (int k = 0; k < 4; k++) {
                const float e = acc[g][2 * k], o = acc[g][2 * k + 1];
                const float give = (lane & 1) ? e : o;
                const float keep = (lane & 1) ? o : e;
                a4[g][k] = keep + __shfl_xor(give, 1);
            }
        float a2[3][2];
#pragma unroll
        for (int g = 0; g < 3; g++)
#pragma unroll
            for (int k = 0; k < 2; k++) {
                const float e = a4[g][2 * k], o = a4[g][2 * k + 1];
                const float give = (lane & 2) ? e : o;
                const float keep = (lane & 2) ? o : e;
                a2[g][k] = keep + __shfl_xor(give, 2);
            }
        float a1[3];
#pragma unroll
        for (int g = 0; g < 3; g++) {
            const float e = a2[g][0], o = a2[g][1];
            const float give = (lane & 4) ? e : o;
            const float keep = (lane & 4) ? o : e;
            a1[g] = keep + __shfl_xor(give, 4);
        }
#pragma unroll
        for (int m = 8; m <= 32; m <<= 1)
#pragma unroll
            for (int g = 0; g < 3; g++) a1[g] += __shfl_xor(a1[g], m);

        // ---- gates on all lanes (a1 valid for c = lane&7 on every lane) ----
        const float r = sigmoidf_(gxr + a1[0] + bh0);
        const float z = sigmoidf_(gxz + a1[1] + bh1);
        const float n = tanhf(gxn + r * (a1[2] + bh2));
        float hnew = (1.f - z) * n + z * hprev;
        hnew = fminf(fmaxf(hnew, -CL), CL);
        const float hodd = __shfl_xor(hnew, 4);
        const unsigned tagst = (((unsigned)t >> 1) & 1u) ^ 1u;
        const unsigned lo = __float_as_uint(hnew) | (tagst << 30);
        const unsigned hi = __float_as_uint(hodd);
        if (lane < 4)
            st_u64_agent(hbuf64 + (size_t)(t & 1) * 4096 +
                             (size_t)(b0 + lane) * 512 + (jb_w >> 1),
                         ((unsigned long long)hi << 32) | lo);
        if (lane < 8)
            out[((size_t)b_l * 2048 + t) * 1024 + j_l] = hnew;
    }
}

extern "C" void kernel_launch(void* const* d_in, const int* in_sizes, int n_in,
                              void* d_out, int out_size, void* d_ws,
                              size_t ws_size, hipStream_t stream) {
    const float* x    = (const float*)d_in[0];
    const float* Wih  = (const float*)d_in[1];
    const float* bih  = (const float*)d_in[2];
    const float* Whh  = (const float*)d_in[3];
    const float* bhh  = (const float*)d_in[4];
    float* outp = (float*)d_out;

    float* xproj = (float*)d_ws;
    unsigned long long* hbuf64 =
        (unsigned long long*)((char*)d_ws + HBUF64_BYTE_OFF);

    dim3 g1(128, 24);   // M/128, N/128
    gemm_xproj<<<g1, 256, 0, stream>>>(x, Wih, bih, xproj);
    gru_scan<<<256, 256, 0, stream>>>(Whh, bhh, xproj, outp, hbuf64);
}

// Round 7
// 11488.425 us; speedup vs baseline: 1.0716x; 1.0707x over previous
//
#include <hip/hip_runtime.h>

#define T_STEPS 2048
#define BATCH 8
#define HID 1024

// ws layout:
//   floats [0, 50331648)      x_proj repacked [b][t][gate][j]: ((b*2048+t)*3+g)*1024 + j
//   byte 201326592 (=192MiB): h double buffer, 2 x 4096 u64, each u64 packs TWO fp32 h
//                             values of a BATCH-pair at one j:
//                             slot = parity*4096 + group*2048 + bp*1024 + j
//                             {hi = h[b=2bp+1][j] clean, lo = h[b=2bp][j] with bit30 = tag}.
//                             production step s -> parity s&1, tagbit(s) = ((s>>1)&1)^1.
//                             |h|<1 (clamped) => real bit30 == 0. ws poison 0xAAAAAAAA has
//                             bit30=0 != tagbit(0)=1, so poison never validates. 64 KiB.
//
// R7-stream-W: R2/R5/R6 proved the register allocator will NEVER carry a 96-float
// loop-invariant W fragment (VGPR 220->sunk reloads, 84->scratch spills; waves_per_eu
// no-op). Pivot: align with the compiler. W is STREAMED per step via inline-asm
// global_load_dwordx4 (un-hoistable, dead after use -> no loop-carried pressure), and
// the stream is made cheap by geometry: G=2 groups x 128 blocks x 512 thr, each wave
// owns ONE j for 4 batches -> every W row is read by exactly one wave per group ->
// device W-stream 24.6MB/step (R1's G=4 layout re-read each row 4x = 49MB/step, the
// hidden ~1.4us/step cost). K-split is contiguous-per-lane float4 (k=4L+256m+e):
// coalesced W loads AND conflict-free ds_read_b128 hv (16/lane vs 128 scalar b32).
#define XPROJ_F 50331648ull
#define HBUF64_BYTE_OFF 201326592ull

typedef float f32x4 __attribute__((ext_vector_type(4)));

__device__ __forceinline__ float sigmoidf_(float x) {
    return 1.0f / (1.0f + __expf(-x));
}

// Relaxed AGENT-scope atomics lower to global_load/store ... sc1 — they read/
// write the Infinity Cache (the inter-XCD coherence point) with NO L2
// writeback/invalidate. An aligned 8B store is single-copy atomic, so the
// packed {tag|h_even, h_odd} packet is self-validating: no flags, no fences.
__device__ __forceinline__ unsigned long long ld_u64_agent(const unsigned long long* p) {
    return __hip_atomic_load(p, __ATOMIC_RELAXED, __HIP_MEMORY_SCOPE_AGENT);
}
__device__ __forceinline__ void st_u64_agent(unsigned long long* p, unsigned long long v) {
    __hip_atomic_store(p, v, __ATOMIC_RELAXED, __HIP_MEMORY_SCOPE_AGENT);
}

// inline-asm W load: asm volatile cannot be hoisted out of the t-loop (the
// address is loop-invariant; a normal load would be hoisted then spilled —
// the R5/R6 pathology). offset is a byte immediate (13-bit signed).
#define LDW(dst, base, off)                                              \
    asm volatile("global_load_dwordx4 %0, %1, off offset:" #off          \
                 : "=v"(dst) : "v"(base) : "memory")

// ---------------- Phase 1: x_proj = x @ W_ih^T + b_ih ----------------
// 128x128 tile, BK=16, 256 threads, 8x8 micro-tile. Epilogue writes the
// [b][t][g][j] layout the scan wants (j-contiguous -> two float4 stores/row).
__global__ __launch_bounds__(256) void gemm_xproj(
        const float* __restrict__ x, const float* __restrict__ Wih,
        const float* __restrict__ bih, float* __restrict__ xproj) {
    __shared__ float a_lds[16][128];  // [k][m]
    __shared__ float b_lds[16][128];  // [k][n]
    const int tid = threadIdx.x;
    const int m0 = blockIdx.x * 128;
    const int n0 = blockIdx.y * 128;
    const int tx = tid & 15, ty = tid >> 4;

    float acc[8][8];
#pragma unroll
    for (int i = 0; i < 8; i++)
#pragma unroll
        for (int jj = 0; jj < 8; jj++) acc[i][jj] = 0.f;

    for (int k0 = 0; k0 < 1024; k0 += 16) {
#pragma unroll
        for (int l = 0; l < 2; l++) {
            const int c = tid + l * 256;
            const int row = c >> 2;
            const int f4 = c & 3;
            float4 av = *reinterpret_cast<const float4*>(
                x + (size_t)(m0 + row) * 1024 + k0 + f4 * 4);
            float4 bv = *reinterpret_cast<const float4*>(
                Wih + (size_t)(n0 + row) * 1024 + k0 + f4 * 4);
            a_lds[f4 * 4 + 0][row] = av.x; a_lds[f4 * 4 + 1][row] = av.y;
            a_lds[f4 * 4 + 2][row] = av.z; a_lds[f4 * 4 + 3][row] = av.w;
            b_lds[f4 * 4 + 0][row] = bv.x; b_lds[f4 * 4 + 1][row] = bv.y;
            b_lds[f4 * 4 + 2][row] = bv.z; b_lds[f4 * 4 + 3][row] = bv.w;
        }
        __syncthreads();
#pragma unroll
        for (int kk = 0; kk < 16; kk++) {
            float a[8], b[8];
            *reinterpret_cast<float4*>(&a[0]) =
                *reinterpret_cast<float4*>(&a_lds[kk][ty * 8]);
            *reinterpret_cast<float4*>(&a[4]) =
                *reinterpret_cast<float4*>(&a_lds[kk][ty * 8 + 4]);
            *reinterpret_cast<float4*>(&b[0]) =
                *reinterpret_cast<float4*>(&b_lds[kk][tx * 8]);
            *reinterpret_cast<float4*>(&b[4]) =
                *reinterpret_cast<float4*>(&b_lds[kk][tx * 8 + 4]);
#pragma unroll
            for (int i = 0; i < 8; i++)
#pragma unroll
                for (int jj = 0; jj < 8; jj++)
                    acc[i][jj] = fmaf(a[i], b[jj], acc[i][jj]);
        }
        __syncthreads();
    }

    float bias[8];
    *reinterpret_cast<float4*>(&bias[0]) =
        *reinterpret_cast<const float4*>(bih + n0 + tx * 8);
    *reinterpret_cast<float4*>(&bias[4]) =
        *reinterpret_cast<const float4*>(bih + n0 + tx * 8 + 4);
    // m = b*T + t; 128-row m-tiles never straddle a batch (T=2048 % 128 == 0).
    // n-tile (128 wide) never straddles a gate (1024 % 128 == 0).
    const int n_base = n0 + tx * 8;
    const int g = n_base >> 10;
    const int j0 = n_base & 1023;
#pragma unroll
    for (int i = 0; i < 8; i++) {
        const int m = m0 + ty * 8 + i;
        const int b = m >> 11;        // m / 2048
        const int t = m & 2047;
        float* dst = xproj + (((size_t)b * 2048 + t) * 3 + g) * 1024 + j0;
        float4 r0 = {acc[i][0] + bias[0], acc[i][1] + bias[1],
                     acc[i][2] + bias[2], acc[i][3] + bias[3]};
        float4 r1 = {acc[i][4] + bias[4], acc[i][5] + bias[5],
                     acc[i][6] + bias[6], acc[i][7] + bias[7]};
        *reinterpret_cast<float4*>(dst) = r0;
        *reinterpret_cast<float4*>(dst + 4) = r1;
    }
}

// ---------------- Phase 2: sequential GRU scan, W streamed per step ----------------
// 256 blocks x 512 threads (8 waves); VGPR modest + 32KB LDS -> 3-4 blocks/CU
// capacity (big residency slack). group = bid&1 (2 groups x 128 blocks) owns
// batches 4g..4g+3 — independent sync domains. Block gb = bid>>1 owns j in
// [gb*8, gb*8+8); wave w owns the single j = gb*8 + w for all 4 batches.
// Per lane: k-chunk {4L+256m+e} (L=lane, m,e=0..3); 3 gates x 4 b x 16 k =
// 192 FMA; W = 12 asm dwordx4 (coalesced, in-flight during the h-poll);
// hv = 16 conflict-free ds_read_b128.
// Per step: gx prefetch -> W prefetch (asm) -> 4 packed-tagged u64 loads ->
// retry stale -> unpack to LDS (dbuf) -> sync -> vmcnt(0)+sched_barrier ->
// matvec -> 21-shuffle fold reduce -> gates -> 2 packed u64 + 4 out stores/wave.
__global__ __launch_bounds__(512, 2) void gru_scan(
        const float* __restrict__ Whh, const float* __restrict__ bhh,
        const float* __restrict__ xproj, float* __restrict__ out,
        unsigned long long* __restrict__ hbuf64) {
    __shared__ float hshare[2][4][HID];   // 32 KB, [parity][b_local][j]
    const int tid = threadIdx.x;
    const int bid = blockIdx.x;
    const int wave = tid >> 6;            // 0..7
    const int lane = tid & 63;
    const int group = bid & 1;            // 2 groups
    const int gb = bid >> 1;              // block within group, 0..127
    const int b0 = group * 4;             // first of this group's 4 batches
    const int jw = gb * 8 + wave;         // wave's single j

    const int bb_l = lane & 3;            // lane's batch (replicated x16)
    const int b_l = b0 + bb_l;

    const float bh0 = bhh[jw];
    const float bh1 = bhh[1024 + jw];
    const float bh2 = bhh[2048 + jw];
    const float CL = 0x1.fffffep-1f;   // largest float < 1: keeps bit30 == 0

    // W row bases for this wave's j (lane's contiguous float4 chunk):
    const float* wrow0 = Whh + (size_t)jw * 1024 + 4 * lane;
    const float* wrow1 = wrow0 + (size_t)1024 * 1024;
    const float* wrow2 = wrow1 + (size_t)1024 * 1024;

    // ---- t = 0: h_prev = 0 -> g_h = b_hh ----
    {
        const size_t xb = ((size_t)b_l * 2048 + 0) * 3072 + jw;
        const float r = sigmoidf_(xproj[xb] + bh0);
        const float z = sigmoidf_(xproj[xb + 1024] + bh1);
        const float n = tanhf(xproj[xb + 2048] + r * bh2);
        float hnew = (1.f - z) * n;
        hnew = fminf(fmaxf(hnew, -CL), CL);
        const float hpair = __shfl_xor(hnew, 1);  // partner batch's value
        const unsigned lo = __float_as_uint(hnew) | (1u << 30);  // tagbit(0)=1
        const unsigned hi = __float_as_uint(hpair);
        if (lane == 0 || lane == 2)   // bp = lane>>1: batch-pair packer
            st_u64_agent(hbuf64 + (size_t)group * 2048 +
                             (size_t)(lane >> 1) * 1024 + jw,
                         ((unsigned long long)hi << 32) | lo);
        if (lane < 4)
            out[((size_t)b_l * 2048) * 1024 + jw] = hnew;
    }

    for (int t = 1; t < T_STEPS; t++) {
        // gx prefetch (cached loads, hidden under the staging/poll)
        const size_t xb = ((size_t)b_l * 2048 + t) * 3072 + jw;
        const float gxr = xproj[xb];
        const float gxz = xproj[xb + 1024];
        const float gxn = xproj[xb + 2048];

        // ---- W prefetch: 12 coalesced dwordx4, in flight during the poll ----
        f32x4 wv0[4], wv1[4], wv2[4];
        LDW(wv0[0], wrow0, 0);    LDW(wv0[1], wrow0, 1024);
        LDW(wv0[2], wrow0, 2048); LDW(wv0[3], wrow0, 3072);
        LDW(wv1[0], wrow1, 0);    LDW(wv1[1], wrow1, 1024);
        LDW(wv1[2], wrow1, 2048); LDW(wv1[3], wrow1, 3072);
        LDW(wv2[0], wrow2, 0);    LDW(wv2[1], wrow2, 1024);
        LDW(wv2[2], wrow2, 2048); LDW(wv2[3], wrow2, 3072);

        // ---- stage h(t-1) for 4 batches: 4 packed tagged u64 loads ----
        const int par = (t - 1) & 1;
        const unsigned long long* src =
            hbuf64 + (size_t)par * 4096 + (size_t)group * 2048;
        const unsigned expect = (((unsigned)(t - 1) >> 1) & 1u) ^ 1u;
        unsigned long long v[4];
#pragma unroll
        for (int i = 0; i < 4; i++)
            v[i] = ld_u64_agent(src + tid + 512 * i);
        for (;;) {
            unsigned bad = 0;
#pragma unroll
            for (int i = 0; i < 4; i++)
                bad |= (((unsigned)(v[i] >> 30)) & 1u) ^ expect;
            if (bad == 0) break;
            __builtin_amdgcn_s_sleep(1);
#pragma unroll
            for (int i = 0; i < 4; i++)
                if ((((unsigned)(v[i] >> 30)) & 1u) != expect)
                    v[i] = ld_u64_agent(src + tid + 512 * i);
        }
#pragma unroll
        for (int i = 0; i < 4; i++) {
            const int s = tid + 512 * i;     // slot = bp*1024 + j
            const int bp = s >> 10;
            const int j = s & 1023;
            hshare[par][2 * bp][j] = __uint_as_float((unsigned)v[i] & 0xBFFFFFFFu);
            hshare[par][2 * bp + 1][j] = __uint_as_float((unsigned)(v[i] >> 32));
        }
        __syncthreads();   // whole block validated + staged h(t-1)
        // (no trailing barrier: next step stages into the other parity half)

        const float hprev = hshare[par][bb_l][jw];

        // the asm-loaded wv regs are invisible to the compiler's waitcnt pass:
        // drain VMEM before first use, and fence scheduling (rule #18).
        asm volatile("s_waitcnt vmcnt(0)" ::: "memory");
        __builtin_amdgcn_sched_barrier(0);

        // ---- matvec: acc[g][bb] over lane's 16-k chunk ----
        float acc0[4], acc1[4], acc2[4];
#pragma unroll
        for (int bb = 0; bb < 4; bb++) { acc0[bb] = 0.f; acc1[bb] = 0.f; acc2[bb] = 0.f; }
#pragma unroll
        for (int bb = 0; bb < 4; bb++) {
#pragma unroll
            for (int m = 0; m < 4; m++) {
                const f32x4 hv = *reinterpret_cast<const f32x4*>(
                    &hshare[par][bb][4 * lane + 256 * m]);
#pragma unroll
                for (int e = 0; e < 4; e++) {
                    acc0[bb] = fmaf(wv0[m][e], hv[e], acc0[bb]);
                    acc1[bb] = fmaf(wv1[m][e], hv[e], acc1[bb]);
                    acc2[bb] = fmaf(wv2[m][e], hv[e], acc2[bb]);
                }
            }
        }

        // ---- value-folding reduce over the 64-way K split ----
        // fold bb bit0 vs lane bit0, bb bit1 vs lane bit1, then 4 butterfly
        // stages; lane l ends with full (r,z,n) sums for bb = l&3. 21 shuffles.
        float r0[2], r1[2], r2[2];
#pragma unroll
        for (int k = 0; k < 2; k++) {
            { const float e = acc0[2 * k], o = acc0[2 * k + 1];
              const float give = (lane & 1) ? e : o, keep = (lane & 1) ? o : e;
              r0[k] = keep + __shfl_xor(give, 1); }
            { const float e = acc1[2 * k], o = acc1[2 * k + 1];
              const float give = (lane & 1) ? e : o, keep = (lane & 1) ? o : e;
              r1[k] = keep + __shfl_xor(give, 1); }
            { const float e = acc2[2 * k], o = acc2[2 * k + 1];
              const float give = (lane & 1) ? e : o, keep = (lane & 1) ? o : e;
              r2[k] = keep + __shfl_xor(give, 1); }
        }
        float a0, a1, a2;
        { const float e = r0[0], o = r0[1];
          const float give = (lane & 2) ? e : o, keep = (lane & 2) ? o : e;
          a0 = keep + __shfl_xor(give, 2); }
        { const float e = r1[0], o = r1[1];
          const float give = (lane & 2) ? e : o, keep = (lane & 2) ? o : e;
          a1 = keep + __shfl_xor(give, 2); }
        { const float e = r2[0], o = r2[1];
          const float give = (lane & 2) ? e : o, keep = (lane & 2) ? o : e;
          a2 = keep + __shfl_xor(give, 2); }
#pragma unroll
        for (int m = 4; m <= 32; m <<= 1) {
            a0 += __shfl_xor(a0, m);
            a1 += __shfl_xor(a1, m);
            a2 += __shfl_xor(a2, m);
        }

        // ---- gates on all lanes (sums valid for bb = lane&3 on every lane) ----
        const float r = sigmoidf_(gxr + a0 + bh0);
        const float z = sigmoidf_(gxz + a1 + bh1);
        const float n = tanhf(gxn + r * (a2 + bh2));
        float hnew = (1.f - z) * n + z * hprev;
        hnew = fminf(fmaxf(hnew, -CL), CL);
        const float hpair = __shfl_xor(hnew, 1);
        const unsigned tagst = (((unsigned)t >> 1) & 1u) ^ 1u;
        const unsigned lo = __float_as_uint(hnew) | (tagst << 30);
        const unsigned hi = __float_as_uint(hpair);
        if (lane == 0 || lane == 2)
            st_u64_agent(hbuf64 + (size_t)(t & 1) * 4096 +
                             (size_t)group * 2048 + (size_t)(lane >> 1) * 1024 + jw,
                         ((unsigned long long)hi << 32) | lo);
        if (lane < 4)
            out[((size_t)b_l * 2048 + t) * 1024 + jw] = hnew;
    }
}

extern "C" void kernel_launch(void* const* d_in, const int* in_sizes, int n_in,
                              void* d_out, int out_size, void* d_ws,
                              size_t ws_size, hipStream_t stream) {
    const float* x    = (const float*)d_in[0];
    const float* Wih  = (const float*)d_in[1];
    const float* bih  = (const float*)d_in[2];
    const float* Whh  = (const float*)d_in[3];
    const float* bhh  = (const float*)d_in[4];
    float* outp = (float*)d_out;

    float* xproj = (float*)d_ws;
    unsigned long long* hbuf64 =
        (unsigned long long*)((char*)d_ws + HBUF64_BYTE_OFF);

    dim3 g1(128, 24);   // M/128, N/128
    gemm_xproj<<<g1, 256, 0, stream>>>(x, Wih, bih, xproj);
    gru_scan<<<256, 512, 0, stream>>>(Whh, bhh, xproj, outp, hbuf64);
}